// Round 8
// baseline (222.440 us; speedup 1.0000x reference)
//
#include <hip/hip_runtime.h>
#include <math.h>

#define NEG_SLOPE 0.2f

typedef float f32x4 __attribute__((ext_vector_type(4)));
typedef short bf16x8 __attribute__((ext_vector_type(8)));
typedef unsigned short ushortv8 __attribute__((ext_vector_type(8)));

__device__ __forceinline__ unsigned short f2bf(float f) {
    union { float f; unsigned u; } uu; uu.f = f;
    unsigned r = uu.u + 0x7FFF + ((uu.u >> 16) & 1);   // RNE, no NaN inputs
    return (unsigned short)(r >> 16);
}
__device__ __forceinline__ float bf2f(unsigned short u) {
    union { unsigned u; float f; } x; x.u = ((unsigned)u) << 16; return x.f;
}

// ---------------------------------------------------------------------------
// prep: x->bf16 convert | W1 transpose | W2 transpose | zero counts+cursor.
// ---------------------------------------------------------------------------
__global__ void prep_kernel(const float* __restrict__ x, unsigned short* __restrict__ xb,
                            const float* __restrict__ W1, unsigned short* __restrict__ Wt1,
                            const float* __restrict__ W2, unsigned short* __restrict__ Wt2,
                            int* __restrict__ counts, int* __restrict__ cursor,
                            int n4x, int N)
{
    int t = blockIdx.x * 256 + threadIdx.x;
    if (t < n4x) {
        float4 v = ((const float4*)x)[t];
        ushort4 o;
        o.x = f2bf(v.x); o.y = f2bf(v.y); o.z = f2bf(v.z); o.w = f2bf(v.w);
        ((ushort4*)xb)[t] = o;
        return;
    }
    int u = t - n4x;
    if (u < 32768) {                       // Wt1[256][128]
        int nn = u >> 7, k = u & 127;
        Wt1[u] = f2bf(W1[(size_t)k * 256 + nn]);
        return;
    }
    u -= 32768;
    if (u < 65536) {                       // Wt2[256][256]
        int nn = u >> 8, k = u & 255;
        Wt2[u] = f2bf(W2[(size_t)k * 256 + nn]);
        return;
    }
    u -= 65536;
    if (u < N) { counts[u] = 0; cursor[u] = 0; }
}

__global__ void hist_kernel(const int* __restrict__ dst, int* __restrict__ counts, int E)
{
    int e = blockIdx.x * 256 + threadIdx.x;
    if (e < E) atomicAdd(&counts[dst[e]], 1);
}

// ---------------------------------------------------------------------------
// MFMA GEMM (verbatim from round-6/7 passing kernel)
// ---------------------------------------------------------------------------
__global__ __launch_bounds__(256) void gemm_mfma(
    const unsigned short* __restrict__ A,
    const unsigned short* __restrict__ Bt,
    unsigned short* __restrict__ C,
    int M, int K)
{
    __shared__ unsigned short As[128 * 64];
    __shared__ unsigned short Bs[128 * 64];
    const int tid  = threadIdx.x;
    const int lane = tid & 63;
    const int wave = tid >> 6;
    const int wr = wave >> 1, wc = wave & 1;
    const int row0 = blockIdx.x * 128;
    const int col0 = blockIdx.y * 128;

    f32x4 acc[4][4] = {};

    for (int k0 = 0; k0 < K; k0 += 64) {
        ushortv8 va[4], vb[4];
        #pragma unroll
        for (int i = 0; i < 4; ++i) {
            int c  = i * 256 + tid;
            int r  = c >> 3, cc = c & 7;
            int ga = row0 + r; if (ga >= M) ga = M - 1;
            va[i] = *(const ushortv8*)(A  + (size_t)ga * K + k0 + cc * 8);
            vb[i] = *(const ushortv8*)(Bt + (size_t)(col0 + r) * K + k0 + cc * 8);
        }
        __syncthreads();
        #pragma unroll
        for (int i = 0; i < 4; ++i) {
            int c  = i * 256 + tid;
            int r  = c >> 3, cc = c & 7;
            int sl = cc ^ (r & 7);
            *(ushortv8*)(As + r * 64 + sl * 8) = va[i];
            *(ushortv8*)(Bs + r * 64 + sl * 8) = vb[i];
        }
        __syncthreads();

        #pragma unroll
        for (int kk = 0; kk < 2; ++kk) {
            const int kbyte = kk * 64 + ((lane >> 4) << 4);
            bf16x8 af[4], bfr[4];
            #pragma unroll
            for (int m = 0; m < 4; ++m) {
                int r = wr * 64 + m * 16 + (lane & 15);
                af[m] = *(const bf16x8*)((const char*)As + r * 128 + (kbyte ^ ((r & 7) << 4)));
            }
            #pragma unroll
            for (int n = 0; n < 4; ++n) {
                int r = wc * 64 + n * 16 + (lane & 15);
                bfr[n] = *(const bf16x8*)((const char*)Bs + r * 128 + (kbyte ^ ((r & 7) << 4)));
            }
            #pragma unroll
            for (int m = 0; m < 4; ++m)
                #pragma unroll
                for (int n = 0; n < 4; ++n)
                    acc[m][n] = __builtin_amdgcn_mfma_f32_16x16x32_bf16(
                        af[m], bfr[n], acc[m][n], 0, 0, 0);
        }
        __syncthreads();
    }

    #pragma unroll
    for (int m = 0; m < 4; ++m) {
        int rbase = row0 + wr * 64 + m * 16 + ((lane >> 4) << 2);
        #pragma unroll
        for (int j = 0; j < 4; ++j) {
            int grow = rbase + j;
            if (grow < M) {
                #pragma unroll
                for (int n = 0; n < 4; ++n)
                    C[(size_t)grow * 256 + col0 + wc * 64 + n * 16 + (lane & 15)] =
                        f2bf(acc[m][n][j]);
            }
        }
    }
}

// ---------------------------------------------------------------------------
// Attention logits from bf16 h. (verbatim)
// ---------------------------------------------------------------------------
__global__ void att_kernel(const unsigned short* __restrict__ h,
                           const float* __restrict__ att_s,
                           const float* __restrict__ att_d,
                           float* __restrict__ a_s, float* __restrict__ a_d, int N)
{
    int t = blockIdx.x * 256 + threadIdx.x;
    if (t >= N * 8) return;
    int n = t >> 3, hh = t & 7;
    const ushortv8* hp = (const ushortv8*)(h + (size_t)n * 256 + hh * 32);
    const float*    ap = att_s + hh * 32;
    const float*    bp = att_d + hh * 32;
    float ss = 0.f, dd = 0.f;
    #pragma unroll
    for (int i = 0; i < 4; ++i) {
        ushortv8 hv = hp[i];
        #pragma unroll
        for (int q = 0; q < 8; ++q) {
            float f = bf2f(hv[q]);
            ss += f * ap[i*8 + q];
            dd += f * bp[i*8 + q];
        }
    }
    a_s[t] = ss; a_d[t] = dd;
}

// ---------------------------------------------------------------------------
// CSR scan kernels (verbatim)
// ---------------------------------------------------------------------------
__global__ __launch_bounds__(256) void scan_blk(
    const int* __restrict__ counts, int* __restrict__ incl, int* __restrict__ bsum, int N)
{
    __shared__ int wtot[4], wexc[4];
    int t = blockIdx.x * 256 + threadIdx.x;
    int lane = threadIdx.x & 63, wid = threadIdx.x >> 6;
    int v = (t < N) ? counts[t] : 0;
    int s = v;
    #pragma unroll
    for (int off = 1; off < 64; off <<= 1) {
        int u = __shfl_up(s, off);
        if (lane >= off) s += u;
    }
    if (lane == 63) wtot[wid] = s;
    __syncthreads();
    if (threadIdx.x == 0) {
        int r = 0;
        #pragma unroll
        for (int w = 0; w < 4; ++w) { wexc[w] = r; r += wtot[w]; }
    }
    __syncthreads();
    int out = s + wexc[wid];
    if (t < N) incl[t] = out;
    if (threadIdx.x == 255) bsum[blockIdx.x] = out;
}

__global__ __launch_bounds__(256) void scan_top(int* __restrict__ bsum, int nb)
{
    __shared__ int wtot[4], wexc[4];
    int tid = threadIdx.x;
    int lane = tid & 63, wid = tid >> 6;
    int v = (tid < nb) ? bsum[tid] : 0;
    int s = v;
    #pragma unroll
    for (int off = 1; off < 64; off <<= 1) {
        int u = __shfl_up(s, off);
        if (lane >= off) s += u;
    }
    if (lane == 63) wtot[wid] = s;
    __syncthreads();
    if (tid == 0) {
        int r = 0;
        #pragma unroll
        for (int w = 0; w < 4; ++w) { wexc[w] = r; r += wtot[w]; }
    }
    __syncthreads();
    if (tid < nb) bsum[tid] = s + wexc[wid] - v;
}

__global__ void fill_kernel(const int* __restrict__ src, const int* __restrict__ dst,
                            const int* __restrict__ incl, const int* __restrict__ bsum,
                            int* __restrict__ rowptr, int* __restrict__ cursor,
                            int* __restrict__ esrc, int N, int E)
{
    int t = blockIdx.x * 256 + threadIdx.x;
    if (t < N) {
        rowptr[t + 1] = incl[t] + bsum[t >> 8];
        if (t == 0) rowptr[0] = 0;
    }
    if (t < E) {
        int d = dst[t];
        int rp = bsum[d >> 8] + ((d & 255) ? incl[d - 1] : 0);
        int pos = rp + atomicAdd(&cursor[d], 1);
        esrc[pos] = src[t];
    }
}

// ---------------------------------------------------------------------------
// Per-node GAT aggregation — NEW geometry (only change this round).
// 2 waves per node: wh=channel half (128 ch each). Within a wave:
// slot=lane>>4 = edge slot (4 edges/gather-instr), sl=lane&15 owns channels
// chb..chb+7 (16B), head = wh*4 + (sl>>2). No-max softmax.
// Slot-combine via shfl_xor(16,32). Layer2 head-mean: xor(4,8) within wave,
// then 512B LDS combine across the 2 channel-half waves.
// deg==0 needs no special case: dsum=0 -> acc*invd=0 -> bias path.
// ---------------------------------------------------------------------------
template<int LAYER>
__global__ __launch_bounds__(256) void gat_agg(
    const unsigned short* __restrict__ h, const float* __restrict__ a_s,
    const float* __restrict__ a_d, const int* __restrict__ rowptr,
    const int* __restrict__ esrc, const float* __restrict__ bias,
    float* __restrict__ out, unsigned short* __restrict__ out_b, int N)
{
    __shared__ float lred[2][2][32];
    const int nslot = threadIdx.x >> 7;          // node within block (0,1)
    const int wh    = (threadIdx.x >> 6) & 1;    // channel half
    const int lane  = threadIdx.x & 63;
    const int slot  = lane >> 4;                 // edge slot 0..3
    const int sl    = lane & 15;                 // 16B chunk within half
    const int head  = wh * 4 + (sl >> 2);
    const int n     = blockIdx.x * 2 + nslot;
    const int chb   = wh * 128 + sl * 8;         // first channel of this lane

    float dsum = 0.f;
    float acc[8] = {0.f,0.f,0.f,0.f,0.f,0.f,0.f,0.f};

    if (n < N) {
        const int beg = rowptr[n];
        const int deg = rowptr[n + 1] - beg;
        const float adn = a_d[(size_t)n*8 + head];

        int j0 = 0;
        for (; j0 + 8 <= deg; j0 += 8) {         // 8 edges: 2 independent quads
            #pragma unroll
            for (int u = 0; u < 2; ++u) {
                int s = esrc[beg + j0 + u*4 + slot];
                float e = a_s[(size_t)s*8 + head] + adn;
                e = (e > 0.f) ? e : NEG_SLOPE * e;
                float p = __expf(e);
                dsum += p;
                ushortv8 hv = *(const ushortv8*)(h + (size_t)s*256 + chb);
                #pragma unroll
                for (int q = 0; q < 8; ++q) acc[q] += p * bf2f(hv[q]);
            }
        }
        if (j0 + 4 <= deg) {                     // one full quad
            int s = esrc[beg + j0 + slot];
            float e = a_s[(size_t)s*8 + head] + adn;
            e = (e > 0.f) ? e : NEG_SLOPE * e;
            float p = __expf(e);
            dsum += p;
            ushortv8 hv = *(const ushortv8*)(h + (size_t)s*256 + chb);
            #pragma unroll
            for (int q = 0; q < 8; ++q) acc[q] += p * bf2f(hv[q]);
            j0 += 4;
        }
        {                                        // partial quad (lane-masked)
            int r = deg - j0;
            if (slot < r) {
                int s = esrc[beg + j0 + slot];
                float e = a_s[(size_t)s*8 + head] + adn;
                e = (e > 0.f) ? e : NEG_SLOPE * e;
                float p = __expf(e);
                dsum += p;
                ushortv8 hv = *(const ushortv8*)(h + (size_t)s*256 + chb);
                #pragma unroll
                for (int q = 0; q < 8; ++q) acc[q] += p * bf2f(hv[q]);
            }
        }

        // combine edge slots (lane bits 4,5)
        dsum += __shfl_xor(dsum, 16);
        dsum += __shfl_xor(dsum, 32);
        #pragma unroll
        for (int q = 0; q < 8; ++q) {
            acc[q] += __shfl_xor(acc[q], 16);
            acc[q] += __shfl_xor(acc[q], 32);
        }
        float invd = 1.f / (dsum + 1e-16f);

        if (LAYER == 1) {
            if (slot == 0) {
                ushortv8 o;
                #pragma unroll
                for (int q = 0; q < 8; ++q) {
                    float val = acc[q] * invd + bias[chb + q];
                    o[q] = f2bf(val > 0.f ? val : (expf(val) - 1.f));
                }
                *(ushortv8*)(out_b + (size_t)n*256 + chb) = o;
            }
        } else {
            #pragma unroll
            for (int q = 0; q < 8; ++q) acc[q] *= invd;
            // sum the 4 heads of this wave (lane bits 2,3)
            #pragma unroll
            for (int q = 0; q < 8; ++q) {
                acc[q] += __shfl_xor(acc[q], 4);
                acc[q] += __shfl_xor(acc[q], 8);
            }
            if (slot == 0 && sl < 4) {
                #pragma unroll
                for (int q = 0; q < 8; ++q) lred[nslot][wh][sl*8 + q] = acc[q];
            }
        }
    }

    if (LAYER == 2) {
        __syncthreads();
        int t = threadIdx.x;
        if (t < 64) {
            int nn = blockIdx.x * 2 + (t >> 5);
            int c = t & 31;
            if (nn < N)
                out[(size_t)nn*32 + c] =
                    (lred[t>>5][0][c] + lred[t>>5][1][c]) * 0.125f + bias[c];
        }
    }
}

// ---------------------------------------------------------------------------
extern "C" void kernel_launch(void* const* d_in, const int* in_sizes, int n_in,
                              void* d_out, int out_size, void* d_ws, size_t ws_size,
                              hipStream_t stream)
{
    const float* x   = (const float*)d_in[0];
    const int*   ei  = (const int*)  d_in[1];
    const float* W1  = (const float*)d_in[2];
    const float* as1 = (const float*)d_in[3];
    const float* ad1 = (const float*)d_in[4];
    const float* b1  = (const float*)d_in[5];
    const float* W2  = (const float*)d_in[6];
    const float* as2 = (const float*)d_in[7];
    const float* ad2 = (const float*)d_in[8];
    const float* b2  = (const float*)d_in[9];

    const int N = in_sizes[0] / 128;
    const int E = in_sizes[1] / 2;
    const int* srcp = ei;
    const int* dstp = ei + E;

    // ---- workspace layout ----
    char* ws = (char*)d_ws;
    unsigned short* hb    = (unsigned short*)ws;  ws += (size_t)N * 256 * 2;
    unsigned short* xb    = (unsigned short*)ws;  ws += (size_t)N * 128 * 2;
    unsigned short* out1b = (unsigned short*)ws;  ws += (size_t)N * 256 * 2;
    unsigned short* Wt1   = (unsigned short*)ws;  ws += 256 * 128 * 2;
    unsigned short* Wt2   = (unsigned short*)ws;  ws += 256 * 256 * 2;
    float*          a_s   = (float*)ws;           ws += (size_t)N * 8 * 4;
    float*          a_d   = (float*)ws;           ws += (size_t)N * 8 * 4;
    int*            counts= (int*)ws;             ws += (size_t)N * 4;
    int*            cursor= (int*)ws;             ws += (size_t)N * 4;
    int*            incl  = (int*)ws;             ws += (size_t)N * 4;
    int*            bsum  = (int*)ws;             ws += 256 * 4;
    int*            rowptr= (int*)ws;             ws += (size_t)(N + 1) * 4;
    int*            esrc  = (int*)ws;

    const int nb  = (N + 255) / 256;
    const int n4x = N * 32;                          // N*128/4

    {
        int tot = n4x + 32768 + 65536 + N;
        prep_kernel<<<(tot + 255) / 256, 256, 0, stream>>>(
            x, xb, W1, Wt1, W2, Wt2, counts, cursor, n4x, N);
    }
    hist_kernel<<<(E + 255) / 256, 256, 0, stream>>>(dstp, counts, E);
    scan_blk<<<nb, 256, 0, stream>>>(counts, incl, bsum, N);
    scan_top<<<1, 256, 0, stream>>>(bsum, nb);
    fill_kernel<<<(E + 255) / 256, 256, 0, stream>>>(srcp, dstp, incl, bsum,
                                                     rowptr, cursor, esrc, N, E);

    const int gridM = (N + 127) / 128;
    const int gridAgg = (N + 1) / 2;

    // ---- layer 1 ----
    gemm_mfma<<<dim3(gridM, 2), 256, 0, stream>>>(xb, Wt1, hb, N, 128);
    att_kernel<<<(N * 8 + 255) / 256, 256, 0, stream>>>(hb, as1, ad1, a_s, a_d, N);
    gat_agg<1><<<gridAgg, 256, 0, stream>>>(hb, a_s, a_d, rowptr, esrc, b1,
                                            nullptr, out1b, N);

    // ---- layer 2 ----
    gemm_mfma<<<dim3(gridM, 2), 256, 0, stream>>>(out1b, Wt2, hb, N, 256);
    att_kernel<<<(N * 8 + 255) / 256, 256, 0, stream>>>(hb, as2, ad2, a_s, a_d, N);
    gat_agg<2><<<gridAgg, 256, 0, stream>>>(hb, a_s, a_d, rowptr, esrc, b2,
                                            (float*)d_out, nullptr, N);
}

// Round 9
// 191.026 us; speedup vs baseline: 1.1644x; 1.1644x over previous
//
#include <hip/hip_runtime.h>
#include <math.h>

#define NEG_SLOPE 0.2f

typedef float f32x4 __attribute__((ext_vector_type(4)));
typedef short bf16x8 __attribute__((ext_vector_type(8)));
typedef unsigned short ushortv8 __attribute__((ext_vector_type(8)));

__device__ __forceinline__ unsigned short f2bf(float f) {
    union { float f; unsigned u; } uu; uu.f = f;
    unsigned r = uu.u + 0x7FFF + ((uu.u >> 16) & 1);   // RNE, no NaN inputs
    return (unsigned short)(r >> 16);
}
__device__ __forceinline__ float bf2f(unsigned short u) {
    union { unsigned u; float f; } x; x.u = ((unsigned)u) << 16; return x.f;
}

// ---------------------------------------------------------------------------
// prep: x->bf16 convert | W1 transpose | W2 transpose | zero counts+cursor.
// ---------------------------------------------------------------------------
__global__ void prep_kernel(const float* __restrict__ x, unsigned short* __restrict__ xb,
                            const float* __restrict__ W1, unsigned short* __restrict__ Wt1,
                            const float* __restrict__ W2, unsigned short* __restrict__ Wt2,
                            int* __restrict__ counts, int* __restrict__ cursor,
                            int n4x, int N)
{
    int t = blockIdx.x * 256 + threadIdx.x;
    if (t < n4x) {
        float4 v = ((const float4*)x)[t];
        ushort4 o;
        o.x = f2bf(v.x); o.y = f2bf(v.y); o.z = f2bf(v.z); o.w = f2bf(v.w);
        ((ushort4*)xb)[t] = o;
        return;
    }
    int u = t - n4x;
    if (u < 32768) {                       // Wt1[256][128]
        int nn = u >> 7, k = u & 127;
        Wt1[u] = f2bf(W1[(size_t)k * 256 + nn]);
        return;
    }
    u -= 32768;
    if (u < 65536) {                       // Wt2[256][256]
        int nn = u >> 8, k = u & 255;
        Wt2[u] = f2bf(W2[(size_t)k * 256 + nn]);
        return;
    }
    u -= 65536;
    if (u < N) { counts[u] = 0; cursor[u] = 0; }
}

__global__ void hist_kernel(const int* __restrict__ dst, int* __restrict__ counts, int E)
{
    int e = blockIdx.x * 256 + threadIdx.x;
    if (e < E) atomicAdd(&counts[dst[e]], 1);
}

// ---------------------------------------------------------------------------
// MFMA GEMM + fused attention-logit epilogue.
// C[M,256]bf16 = A@Bt; additionally a_s[n,h], a_d[n,h] for the 4 heads this
// col-block owns (heads = blockIdx.y*4 + wc*2 + t; head h's 32 cols are
// frags n=2t,2t+1), reduced from the f32 accumulators over lane&15.
// ---------------------------------------------------------------------------
__global__ __launch_bounds__(256) void gemm_mfma(
    const unsigned short* __restrict__ A,
    const unsigned short* __restrict__ Bt,
    unsigned short* __restrict__ C,
    const float* __restrict__ att_s,    // flat [256]: [h][c] with col=h*32+c
    const float* __restrict__ att_d,
    float* __restrict__ a_s,            // [M][8]
    float* __restrict__ a_d,
    int M, int K)
{
    __shared__ unsigned short As[128 * 64];
    __shared__ unsigned short Bs[128 * 64];
    const int tid  = threadIdx.x;
    const int lane = tid & 63;
    const int wave = tid >> 6;
    const int wr = wave >> 1, wc = wave & 1;
    const int row0 = blockIdx.x * 128;
    const int col0 = blockIdx.y * 128;

    f32x4 acc[4][4] = {};

    for (int k0 = 0; k0 < K; k0 += 64) {
        ushortv8 va[4], vb[4];
        #pragma unroll
        for (int i = 0; i < 4; ++i) {
            int c  = i * 256 + tid;
            int r  = c >> 3, cc = c & 7;
            int ga = row0 + r; if (ga >= M) ga = M - 1;
            va[i] = *(const ushortv8*)(A  + (size_t)ga * K + k0 + cc * 8);
            vb[i] = *(const ushortv8*)(Bt + (size_t)(col0 + r) * K + k0 + cc * 8);
        }
        __syncthreads();
        #pragma unroll
        for (int i = 0; i < 4; ++i) {
            int c  = i * 256 + tid;
            int r  = c >> 3, cc = c & 7;
            int sl = cc ^ (r & 7);
            *(ushortv8*)(As + r * 64 + sl * 8) = va[i];
            *(ushortv8*)(Bs + r * 64 + sl * 8) = vb[i];
        }
        __syncthreads();

        #pragma unroll
        for (int kk = 0; kk < 2; ++kk) {
            const int kbyte = kk * 64 + ((lane >> 4) << 4);
            bf16x8 af[4], bfr[4];
            #pragma unroll
            for (int m = 0; m < 4; ++m) {
                int r = wr * 64 + m * 16 + (lane & 15);
                af[m] = *(const bf16x8*)((const char*)As + r * 128 + (kbyte ^ ((r & 7) << 4)));
            }
            #pragma unroll
            for (int n = 0; n < 4; ++n) {
                int r = wc * 64 + n * 16 + (lane & 15);
                bfr[n] = *(const bf16x8*)((const char*)Bs + r * 128 + (kbyte ^ ((r & 7) << 4)));
            }
            #pragma unroll
            for (int m = 0; m < 4; ++m)
                #pragma unroll
                for (int n = 0; n < 4; ++n)
                    acc[m][n] = __builtin_amdgcn_mfma_f32_16x16x32_bf16(
                        af[m], bfr[n], acc[m][n], 0, 0, 0);
        }
        __syncthreads();
    }

    // ---- C store ----
    #pragma unroll
    for (int m = 0; m < 4; ++m) {
        int rbase = row0 + wr * 64 + m * 16 + ((lane >> 4) << 2);
        #pragma unroll
        for (int j = 0; j < 4; ++j) {
            int grow = rbase + j;
            if (grow < M) {
                #pragma unroll
                for (int n = 0; n < 4; ++n)
                    C[(size_t)grow * 256 + col0 + wc * 64 + n * 16 + (lane & 15)] =
                        f2bf(acc[m][n][j]);
            }
        }
    }

    // ---- fused attention logits ----
    // per-lane att coefficients for the 4 col-frags
    float asv[4], adv[4];
    #pragma unroll
    for (int n = 0; n < 4; ++n) {
        int colg = col0 + wc * 64 + n * 16 + (lane & 15);
        asv[n] = att_s[colg];
        adv[n] = att_d[colg];
    }
    const int hbase = blockIdx.y * 4 + wc * 2;
    #pragma unroll
    for (int m = 0; m < 4; ++m) {
        int rbase = row0 + wr * 64 + m * 16 + ((lane >> 4) << 2);
        #pragma unroll
        for (int j = 0; j < 4; ++j) {
            int grow = rbase + j;
            #pragma unroll
            for (int t = 0; t < 2; ++t) {
                float vs = acc[m][2*t][j] * asv[2*t] + acc[m][2*t+1][j] * asv[2*t+1];
                float vd = acc[m][2*t][j] * adv[2*t] + acc[m][2*t+1][j] * adv[2*t+1];
                #pragma unroll
                for (int off = 1; off < 16; off <<= 1) {
                    vs += __shfl_xor(vs, off);
                    vd += __shfl_xor(vd, off);
                }
                if ((lane & 15) == 0 && grow < M) {
                    a_s[(size_t)grow * 8 + hbase + t] = vs;
                    a_d[(size_t)grow * 8 + hbase + t] = vd;
                }
            }
        }
    }
}

// ---------------------------------------------------------------------------
// CSR scan kernels (verbatim)
// ---------------------------------------------------------------------------
__global__ __launch_bounds__(256) void scan_blk(
    const int* __restrict__ counts, int* __restrict__ incl, int* __restrict__ bsum, int N)
{
    __shared__ int wtot[4], wexc[4];
    int t = blockIdx.x * 256 + threadIdx.x;
    int lane = threadIdx.x & 63, wid = threadIdx.x >> 6;
    int v = (t < N) ? counts[t] : 0;
    int s = v;
    #pragma unroll
    for (int off = 1; off < 64; off <<= 1) {
        int u = __shfl_up(s, off);
        if (lane >= off) s += u;
    }
    if (lane == 63) wtot[wid] = s;
    __syncthreads();
    if (threadIdx.x == 0) {
        int r = 0;
        #pragma unroll
        for (int w = 0; w < 4; ++w) { wexc[w] = r; r += wtot[w]; }
    }
    __syncthreads();
    int out = s + wexc[wid];
    if (t < N) incl[t] = out;
    if (threadIdx.x == 255) bsum[blockIdx.x] = out;
}

__global__ __launch_bounds__(256) void scan_top(int* __restrict__ bsum, int nb)
{
    __shared__ int wtot[4], wexc[4];
    int tid = threadIdx.x;
    int lane = tid & 63, wid = tid >> 6;
    int v = (tid < nb) ? bsum[tid] : 0;
    int s = v;
    #pragma unroll
    for (int off = 1; off < 64; off <<= 1) {
        int u = __shfl_up(s, off);
        if (lane >= off) s += u;
    }
    if (lane == 63) wtot[wid] = s;
    __syncthreads();
    if (tid == 0) {
        int r = 0;
        #pragma unroll
        for (int w = 0; w < 4; ++w) { wexc[w] = r; r += wtot[w]; }
    }
    __syncthreads();
    if (tid < nb) bsum[tid] = s + wexc[wid] - v;
}

__global__ void fill_kernel(const int* __restrict__ src, const int* __restrict__ dst,
                            const int* __restrict__ incl, const int* __restrict__ bsum,
                            int* __restrict__ rowptr, int* __restrict__ cursor,
                            int* __restrict__ esrc, int N, int E)
{
    int t = blockIdx.x * 256 + threadIdx.x;
    if (t < N) {
        rowptr[t + 1] = incl[t] + bsum[t >> 8];
        if (t == 0) rowptr[0] = 0;
    }
    if (t < E) {
        int d = dst[t];
        int rp = bsum[d >> 8] + ((d & 255) ? incl[d - 1] : 0);
        int pos = rp + atomicAdd(&cursor[d], 1);
        esrc[pos] = src[t];
    }
}

// ---------------------------------------------------------------------------
// Per-node GAT aggregation — round-6 best variant, verbatim.
// One wave per node (4/block). half=lane>>5 handles every other edge;
// sl=lane&31 owns channels sl*8..sl*8+7 (16B gather); head=sl>>2.
// No-max softmax; half-combine via single shfl_xor(32).
// ---------------------------------------------------------------------------
template<int LAYER>
__global__ __launch_bounds__(256) void gat_agg(
    const unsigned short* __restrict__ h, const float* __restrict__ a_s,
    const float* __restrict__ a_d, const int* __restrict__ rowptr,
    const int* __restrict__ esrc, const float* __restrict__ bias,
    float* __restrict__ out, unsigned short* __restrict__ out_b, int N)
{
    int n = blockIdx.x * 4 + (threadIdx.x >> 6);
    if (n >= N) return;
    const int lane = threadIdx.x & 63;
    const int half = lane >> 5;
    const int sl   = lane & 31;
    const int head = sl >> 2;
    int beg = rowptr[n];
    int deg = rowptr[n + 1] - beg;

    if (deg == 0) {
        if (LAYER == 1) {
            if (half == 0) {
                ushortv8 o;
                #pragma unroll
                for (int q = 0; q < 8; ++q) {
                    float b = bias[sl*8 + q];
                    o[q] = f2bf(b > 0.f ? b : expf(b) - 1.f);
                }
                *(ushortv8*)(out_b + (size_t)n*256 + sl*8) = o;
            }
        } else {
            if (lane < 4) {
                #pragma unroll
                for (int q = 0; q < 8; ++q)
                    out[(size_t)n*32 + lane*8 + q] = bias[lane*8 + q];
            }
        }
        return;
    }

    float adn = a_d[(size_t)n*8 + head];
    float dsum = 0.f;
    float acc[8] = {0.f,0.f,0.f,0.f,0.f,0.f,0.f,0.f};

    int j0 = 0;
    for (; j0 + 8 <= deg; j0 += 8) {
        int s0 = esrc[beg + j0 + 0 + half];
        int s1 = esrc[beg + j0 + 2 + half];
        int s2 = esrc[beg + j0 + 4 + half];
        int s3 = esrc[beg + j0 + 6 + half];
        int sv[4] = {s0, s1, s2, s3};
        #pragma unroll
        for (int k = 0; k < 4; ++k) {
            int s = sv[k];
            float e = a_s[(size_t)s*8 + head] + adn;
            e = (e > 0.f) ? e : NEG_SLOPE * e;
            float p = __expf(e);
            dsum += p;
            ushortv8 hv = *(const ushortv8*)(h + (size_t)s*256 + sl*8);
            #pragma unroll
            for (int q = 0; q < 8; ++q) acc[q] += p * bf2f(hv[q]);
        }
    }
    for (; j0 + 2 <= deg; j0 += 2) {
        int s = esrc[beg + j0 + half];
        float e = a_s[(size_t)s*8 + head] + adn;
        e = (e > 0.f) ? e : NEG_SLOPE * e;
        float p = __expf(e);
        dsum += p;
        ushortv8 hv = *(const ushortv8*)(h + (size_t)s*256 + sl*8);
        #pragma unroll
        for (int q = 0; q < 8; ++q) acc[q] += p * bf2f(hv[q]);
    }
    if (j0 < deg) {                      // single leftover edge (half 0 only)
        int s = esrc[beg + j0];
        if (half == 0) {
            float e = a_s[(size_t)s*8 + head] + adn;
            e = (e > 0.f) ? e : NEG_SLOPE * e;
            float p = __expf(e);
            dsum += p;
            ushortv8 hv = *(const ushortv8*)(h + (size_t)s*256 + sl*8);
            #pragma unroll
            for (int q = 0; q < 8; ++q) acc[q] += p * bf2f(hv[q]);
        }
    }

    // combine the two halves
    dsum += __shfl_xor(dsum, 32);
    #pragma unroll
    for (int q = 0; q < 8; ++q) acc[q] += __shfl_xor(acc[q], 32);
    float invd = 1.f / (dsum + 1e-16f);

    if (LAYER == 1) {
        if (half == 0) {
            ushortv8 o;
            #pragma unroll
            for (int q = 0; q < 8; ++q) {
                float val = acc[q] * invd + bias[sl*8 + q];
                o[q] = f2bf(val > 0.f ? val : expf(val) - 1.f);
            }
            *(ushortv8*)(out_b + (size_t)n*256 + sl*8) = o;
        }
    } else {
        #pragma unroll
        for (int q = 0; q < 8; ++q) acc[q] *= invd;
        // mean across heads: heads live on lane bits 2..4
        #pragma unroll
        for (int m = 4; m <= 16; m <<= 1)
            #pragma unroll
            for (int q = 0; q < 8; ++q) acc[q] += __shfl_xor(acc[q], m);
        if (lane < 4) {
            float4 lo = make_float4(acc[0]*0.125f + bias[lane*8+0],
                                    acc[1]*0.125f + bias[lane*8+1],
                                    acc[2]*0.125f + bias[lane*8+2],
                                    acc[3]*0.125f + bias[lane*8+3]);
            float4 hi = make_float4(acc[4]*0.125f + bias[lane*8+4],
                                    acc[5]*0.125f + bias[lane*8+5],
                                    acc[6]*0.125f + bias[lane*8+6],
                                    acc[7]*0.125f + bias[lane*8+7]);
            *(float4*)(out + (size_t)n*32 + lane*8)     = lo;
            *(float4*)(out + (size_t)n*32 + lane*8 + 4) = hi;
        }
    }
}

// ---------------------------------------------------------------------------
extern "C" void kernel_launch(void* const* d_in, const int* in_sizes, int n_in,
                              void* d_out, int out_size, void* d_ws, size_t ws_size,
                              hipStream_t stream)
{
    const float* x   = (const float*)d_in[0];
    const int*   ei  = (const int*)  d_in[1];
    const float* W1  = (const float*)d_in[2];
    const float* as1 = (const float*)d_in[3];
    const float* ad1 = (const float*)d_in[4];
    const float* b1  = (const float*)d_in[5];
    const float* W2  = (const float*)d_in[6];
    const float* as2 = (const float*)d_in[7];
    const float* ad2 = (const float*)d_in[8];
    const float* b2  = (const float*)d_in[9];

    const int N = in_sizes[0] / 128;
    const int E = in_sizes[1] / 2;
    const int* srcp = ei;
    const int* dstp = ei + E;

    // ---- workspace layout ----
    char* ws = (char*)d_ws;
    unsigned short* hb    = (unsigned short*)ws;  ws += (size_t)N * 256 * 2;
    unsigned short* xb    = (unsigned short*)ws;  ws += (size_t)N * 128 * 2;
    unsigned short* out1b = (unsigned short*)ws;  ws += (size_t)N * 256 * 2;
    unsigned short* Wt1   = (unsigned short*)ws;  ws += 256 * 128 * 2;
    unsigned short* Wt2   = (unsigned short*)ws;  ws += 256 * 256 * 2;
    float*          a_s   = (float*)ws;           ws += (size_t)N * 8 * 4;
    float*          a_d   = (float*)ws;           ws += (size_t)N * 8 * 4;
    int*            counts= (int*)ws;             ws += (size_t)N * 4;
    int*            cursor= (int*)ws;             ws += (size_t)N * 4;
    int*            incl  = (int*)ws;             ws += (size_t)N * 4;
    int*            bsum  = (int*)ws;             ws += 256 * 4;
    int*            rowptr= (int*)ws;             ws += (size_t)(N + 1) * 4;
    int*            esrc  = (int*)ws;

    const int nb  = (N + 255) / 256;
    const int n4x = N * 32;                          // N*128/4

    {
        int tot = n4x + 32768 + 65536 + N;
        prep_kernel<<<(tot + 255) / 256, 256, 0, stream>>>(
            x, xb, W1, Wt1, W2, Wt2, counts, cursor, n4x, N);
    }
    hist_kernel<<<(E + 255) / 256, 256, 0, stream>>>(dstp, counts, E);
    scan_blk<<<nb, 256, 0, stream>>>(counts, incl, bsum, N);
    scan_top<<<1, 256, 0, stream>>>(bsum, nb);
    fill_kernel<<<(E + 255) / 256, 256, 0, stream>>>(srcp, dstp, incl, bsum,
                                                     rowptr, cursor, esrc, N, E);

    const int gridM = (N + 127) / 128;

    // ---- layer 1 (att fused into GEMM epilogue) ----
    gemm_mfma<<<dim3(gridM, 2), 256, 0, stream>>>(xb, Wt1, hb, as1, ad1,
                                                  a_s, a_d, N, 128);
    gat_agg<1><<<(N + 3) / 4, 256, 0, stream>>>(hb, a_s, a_d, rowptr, esrc, b1,
                                                nullptr, out1b, N);

    // ---- layer 2 ----
    gemm_mfma<<<dim3(gridM, 2), 256, 0, stream>>>(out1b, Wt2, hb, as2, ad2,
                                                  a_s, a_d, N, 256);
    gat_agg<2><<<(N + 3) / 4, 256, 0, stream>>>(hb, a_s, a_d, rowptr, esrc, b2,
                                                (float*)d_out, nullptr, N);
}